// Round 10
// baseline (126.494 us; speedup 1.0000x reference)
//
#include <hip/hip_runtime.h>

// Problem constants
#define B_DIM   4096
#define C_DIM   128
#define P_IDS   256          // B/K_INST
#define INV_TEMP 20.0f       // 1/0.05
#define EPS 1e-6f

#define A_CHUNKS 65536       // 4096*128/8  (bf16x8 chunks)
#define B_CHUNKS 524288      // 32768*128/8
#define ALL_CHUNKS (A_CHUNKS + B_CHUNKS)

typedef unsigned short u16;
typedef __attribute__((ext_vector_type(8))) short bf16x8;
typedef __attribute__((ext_vector_type(4))) float f32x4;

__device__ __forceinline__ u16 f2bf(float x) {
    union { float f; unsigned u; } v; v.f = x;
    unsigned r = v.u + 0x7fffu + ((v.u >> 16) & 1u);   // RTN-even
    return (u16)(r >> 16);
}

// ---------------- kernel 1: fp32 -> bf16 fragment-tiled A and B ----------------
// Chunk c (16B = 8 bf16): grow=c2>>8, kk=(c2>>6)&3, lane=c2&63, g=lane>>4,
// r=lane&15 -> holds SRC[grow*16 + r][kk*32 + g*8 .. +8].
// Chunks 0..65535 = feats (A), 65536.. = feats_s (B). Boundary block-aligned.
__global__ __launch_bounds__(256) void convert_bf16(const float* __restrict__ feats,
                                                    const float* __restrict__ feats_s,
                                                    u16* __restrict__ T) {
    const int c = blockIdx.x * 256 + threadIdx.x;
    const float* base; int c2;
    if (c < A_CHUNKS) { base = feats;   c2 = c; }
    else              { base = feats_s; c2 = c - A_CHUNKS; }
    const int grow = c2 >> 8, kk = (c2 >> 6) & 3, lane = c2 & 63;
    const int g = lane >> 4, r = lane & 15;
    const float* src = base + (size_t)(grow * 16 + r) * C_DIM + kk * 32 + g * 8;
    float4 u0 = *(const float4*)src;
    float4 u1 = *(const float4*)(src + 4);
    bf16x8 o;
    o[0] = (short)f2bf(u0.x); o[1] = (short)f2bf(u0.y);
    o[2] = (short)f2bf(u0.z); o[3] = (short)f2bf(u0.w);
    o[4] = (short)f2bf(u1.x); o[5] = (short)f2bf(u1.y);
    o[6] = (short)f2bf(u1.z); o[7] = (short)f2bf(u1.w);
    *(bf16x8*)(T + (size_t)c * 8) = o;
}

// ---------------- kernel 2: zero-LDS streaming sim, full-width waves ----------------
// R17 vs R16 (112.1; phase1 ~40 us stable across FIVE structures R11-R16 ->
// B-handling/latency/TLP all exonerated):
//  * Remaining arithmetic: old structure's wn-pair waves read the SAME 512
//    A-rows twice -> 2 MB/CU of L2->VGPR A-traffic (~15.6 us at 56 B/cyc/CU),
//    same magnitude as the 16.6 us MFMA floor; poor overlap ~= observed 40.
//  * Fix: 4 waves = 4 ROW-QUARTERS, each wave covers ALL 128 support cols of
//    identity p. A loaded exactly once per block: 1 MB/CU (~8 us, hidable).
//    b[8][4] = 128 VGPRs (opacity-pinned), live ~220 <= 256 at (256,2).
//    32 MFMAs/step (~620 SIMD-cyc) -> depth-1 prefetch covers L2 latency.
//  * Full 128-col max folds in-register: pmax halves to [256][4096], pmin
//    to [4096]; phase2 loses the fmax-of-halves pass.
// Retained: zero LDS / zero barriers, pre-tiled bf16 A+B, opacity barrier
// (remat impossible), swapped MFMA operands, exclusive 64B-line stores.
__global__ __launch_bounds__(256, 2) void phase1(const u16*  __restrict__ T,   // frag-tiled bf16: A then B
                                                 float* __restrict__ pmax,     // [256][4096]
                                                 float* __restrict__ pmin)     // [4096]
{
    const int tid  = threadIdx.x;
    const int lane = tid & 63;
    const int w    = tid >> 6;        // row quarter within block (256 rows each)
    const int p    = blockIdx.x;      // identity 0..255
    const int h    = blockIdx.y;      // row quarter of B_DIM: rows h*1024..+1023

    // ---- B fragments: 32 one-time global loads -> 128 VGPRs, then OPAQUE ----
    // b[ni][kk] holds B[p*128 + ni*16 + (lane&15)][kk*32 + (lane>>4)*8 .. +8]
    const u16* bbase = T + (size_t)A_CHUNKS * 8 + ((size_t)(p * 8) * 256 + lane) * 8;
    bf16x8 b[8][4];
#pragma unroll
    for (int ni = 0; ni < 8; ++ni)
#pragma unroll
        for (int kk = 0; kk < 4; ++kk)
            b[ni][kk] = *(const bf16x8*)(bbase + ni * 2048 + kk * 512);
    // Opacity barrier: origin unknowable -> rematerialization impossible.
#pragma unroll
    for (int ni = 0; ni < 8; ++ni)
#pragma unroll
        for (int kk = 0; kk < 4; ++kk)
            asm volatile("" : "+v"(b[ni][kk]));

    // ---- A stream: 16 steps of 16 rows (wave's 256-row quarter) ----
    const int grow0 = h * 64 + w * 16;                       // 16-row group base
    const u16* abase = T + ((size_t)grow0 * 256 + lane) * 8; // +ss*2048, +kk*512 (u16)

    // pmax [p][row]: wave owns rows h*1024 + w*256 .. +255
    float* const pq = pmax + (size_t)p * B_DIM + h * 1024 + w * 256;
    const bool dhit = (h == (p >> 6)) && (w == ((p >> 4) & 3));
    const int  ssel = p & 15;

#define LOADA(dst, ss) do { const u16* ap = abase + (size_t)(ss) * 2048;         \
        dst[0] = *(const bf16x8*)ap;         dst[1] = *(const bf16x8*)(ap + 512); \
        dst[2] = *(const bf16x8*)(ap + 1024); dst[3] = *(const bf16x8*)(ap + 1536); } while (0)

    // D[n][m] per lane (operands swapped): col(lane&15)=A-row (anchor),
    // row(g*4+rr)=B-col (support). acc[ni] covers support cols ni*16..+15.
#define STEP(areg, ss) do {                                                       \
        f32x4 acc[8] = {};                                                        \
        _Pragma("unroll")                                                         \
        for (int kk = 0; kk < 4; ++kk) {                                          \
            _Pragma("unroll")                                                     \
            for (int ni = 0; ni < 8; ++ni)                                        \
                acc[ni] = __builtin_amdgcn_mfma_f32_16x16x32_bf16(                \
                    b[ni][kk], areg[kk], acc[ni], 0, 0, 0);                       \
        }                                                                         \
        float t0 = fmaxf(fmaxf(acc[0][0], acc[0][1]), fmaxf(acc[0][2], acc[0][3]));\
        float t1 = fmaxf(fmaxf(acc[1][0], acc[1][1]), fmaxf(acc[1][2], acc[1][3]));\
        float t2 = fmaxf(fmaxf(acc[2][0], acc[2][1]), fmaxf(acc[2][2], acc[2][3]));\
        float t3 = fmaxf(fmaxf(acc[3][0], acc[3][1]), fmaxf(acc[3][2], acc[3][3]));\
        float t4 = fmaxf(fmaxf(acc[4][0], acc[4][1]), fmaxf(acc[4][2], acc[4][3]));\
        float t5 = fmaxf(fmaxf(acc[5][0], acc[5][1]), fmaxf(acc[5][2], acc[5][3]));\
        float t6 = fmaxf(fmaxf(acc[6][0], acc[6][1]), fmaxf(acc[6][2], acc[6][3]));\
        float t7 = fmaxf(fmaxf(acc[7][0], acc[7][1]), fmaxf(acc[7][2], acc[7][3]));\
        float mx = fmaxf(fmaxf(fmaxf(t0, t1), fmaxf(t2, t3)),                     \
                         fmaxf(fmaxf(t4, t5), fmaxf(t6, t7)));                    \
        mx = fmaxf(mx, __shfl_xor(mx, 16, 64));                                   \
        mx = fmaxf(mx, __shfl_xor(mx, 32, 64));                                   \
        if (lane < 16) pq[(ss) * 16 + lane] = mx;                                 \
        if (dhit && (ss) == ssel) {                                               \
            float n0 = fminf(fminf(acc[0][0], acc[0][1]), fminf(acc[0][2], acc[0][3]));\
            float n1 = fminf(fminf(acc[1][0], acc[1][1]), fminf(acc[1][2], acc[1][3]));\
            float n2 = fminf(fminf(acc[2][0], acc[2][1]), fminf(acc[2][2], acc[2][3]));\
            float n3 = fminf(fminf(acc[3][0], acc[3][1]), fminf(acc[3][2], acc[3][3]));\
            float n4 = fminf(fminf(acc[4][0], acc[4][1]), fminf(acc[4][2], acc[4][3]));\
            float n5 = fminf(fminf(acc[5][0], acc[5][1]), fminf(acc[5][2], acc[5][3]));\
            float n6 = fminf(fminf(acc[6][0], acc[6][1]), fminf(acc[6][2], acc[6][3]));\
            float n7 = fminf(fminf(acc[7][0], acc[7][1]), fminf(acc[7][2], acc[7][3]));\
            float mn = fminf(fminf(fminf(n0, n1), fminf(n2, n3)),                 \
                             fminf(fminf(n4, n5), fminf(n6, n7)));                \
            mn = fminf(mn, __shfl_xor(mn, 16, 64));                               \
            mn = fminf(mn, __shfl_xor(mn, 32, 64));                               \
            if (lane < 16) pmin[p * 16 + lane] = mn;                              \
        }                                                                         \
    } while (0)

    bf16x8 aA[4], aB[4];
    LOADA(aA, 0);
#pragma unroll 1
    for (int s = 0; s < 16; s += 2) {
        LOADA(aB, s + 1);             // prefetch odd step
        STEP(aA, s);
        if (s + 2 < 16) LOADA(aA, s + 2);  // prefetch next even step
        STEP(aB, s + 1);
    }
#undef LOADA
#undef STEP
}

// ---------------- kernel 3: per-row loss + mean (stripe-transposed reads) ----------------
// 64 blocks x 256 thr. Block owns a 64-row stripe; lane = row, wave owns a
// 64-wide p-range. Every pmax load is a coalesced 256B line (L2-resident).
__global__ __launch_bounds__(256) void phase2(const float* __restrict__ pmax,  // [256][4096]
                                              const float* __restrict__ pmin,  // [4096]
                                              const int* __restrict__ labels,
                                              float* __restrict__ out) {
    const int tid  = threadIdx.x;
    const int lane = tid & 63;
    const int wave = tid >> 6;
    const int row  = blockIdx.x * 64 + lane;
    const int pid  = labels[row];
    const float* q = pmax + (size_t)(wave * 64) * B_DIM + row;    // p = wave*64+j
    float s = 0.f;
#pragma unroll 8
    for (int j = 0; j < 64; ++j) {
        const int p = wave * 64 + j;
        const float v = q[(size_t)j * B_DIM];
        s += (p == pid) ? 0.f : __expf(v * INV_TEMP);
    }
    __shared__ float part[4][64];
    part[wave][lane] = s;
    __syncthreads();
    if (wave == 0) {
        const float neg = part[0][lane] + part[1][lane] + part[2][lane] + part[3][lane];
        const float pos = __expf(pmin[row] * INV_TEMP);
        float loss = -__logf(pos / (pos + neg + EPS) + EPS);
        loss += __shfl_xor(loss, 1, 64);
        loss += __shfl_xor(loss, 2, 64);
        loss += __shfl_xor(loss, 4, 64);
        loss += __shfl_xor(loss, 8, 64);
        loss += __shfl_xor(loss, 16, 64);
        loss += __shfl_xor(loss, 32, 64);
        if (lane == 0) atomicAdd(out, loss * (1.0f / (float)B_DIM));
    }
}

extern "C" void kernel_launch(void* const* d_in, const int* in_sizes, int n_in,
                              void* d_out, int out_size, void* d_ws, size_t ws_size,
                              hipStream_t stream) {
    const float* feats   = (const float*)d_in[0];   // [4096,128]
    const float* feats_s = (const float*)d_in[1];   // [4096,8,128] fp32
    const int*   labels  = (const int*)d_in[2];     // [4096]
    float* out = (float*)d_out;

    // workspace: T = frag-tiled bf16 A(1 MB)+B(8 MB) | pmax (4 MB) | pmin (16 KB)
    u16* T = (u16*)d_ws;
    float* pmax = (float*)((char*)d_ws + (16u << 20));
    float* pmin = pmax + (size_t)P_IDS * B_DIM;

    hipMemsetAsync(d_out, 0, sizeof(float), stream);
    convert_bf16<<<ALL_CHUNKS / 256, 256, 0, stream>>>(feats, feats_s, T);
    dim3 g1(P_IDS, 4);
    phase1<<<g1, 256, 0, stream>>>(T, pmax, pmin);
    phase2<<<B_DIM / 64, 256, 0, stream>>>(pmax, pmin, labels, out);
}

// Round 12
// 114.308 us; speedup vs baseline: 1.1066x; 1.1066x over previous
//
#include <hip/hip_runtime.h>

// Problem constants
#define B_DIM   4096
#define C_DIM   128
#define P_IDS   256          // B/K_INST
#define INV_TEMP 20.0f       // 1/0.05
#define EPS 1e-6f

#define A_CHUNKS 65536       // 4096*128/8  (bf16x8 chunks)
#define B_CHUNKS 524288      // 32768*128/8
#define ALL_CHUNKS (A_CHUNKS + B_CHUNKS)

typedef unsigned short u16;
typedef __attribute__((ext_vector_type(8))) short bf16x8;
typedef __attribute__((ext_vector_type(4))) float f32x4;

__device__ __forceinline__ u16 f2bf(float x) {
    union { float f; unsigned u; } v; v.f = x;
    unsigned r = v.u + 0x7fffu + ((v.u >> 16) & 1u);   // RTN-even
    return (u16)(r >> 16);
}

// ---------------- kernel 1: fp32 -> bf16 fragment-tiled A and B ----------------
// Chunk c (16B = 8 bf16): grow=c2>>8, kk=(c2>>6)&3, lane=c2&63, g=lane>>4,
// r=lane&15 -> holds SRC[grow*16 + r][kk*32 + g*8 .. +8].
// Chunks 0..65535 = feats (A), 65536.. = feats_s (B). Boundary block-aligned.
__global__ __launch_bounds__(256) void convert_bf16(const float* __restrict__ feats,
                                                    const float* __restrict__ feats_s,
                                                    u16* __restrict__ T) {
    const int c = blockIdx.x * 256 + threadIdx.x;
    const float* base; int c2;
    if (c < A_CHUNKS) { base = feats;   c2 = c; }
    else              { base = feats_s; c2 = c - A_CHUNKS; }
    const int grow = c2 >> 8, kk = (c2 >> 6) & 3, lane = c2 & 63;
    const int g = lane >> 4, r = lane & 15;
    const float* src = base + (size_t)(grow * 16 + r) * C_DIM + kk * 32 + g * 8;
    float4 u0 = *(const float4*)src;
    float4 u1 = *(const float4*)(src + 4);
    bf16x8 o;
    o[0] = (short)f2bf(u0.x); o[1] = (short)f2bf(u0.y);
    o[2] = (short)f2bf(u0.z); o[3] = (short)f2bf(u0.w);
    o[4] = (short)f2bf(u1.x); o[5] = (short)f2bf(u1.y);
    o[6] = (short)f2bf(u1.z); o[7] = (short)f2bf(u1.w);
    *(bf16x8*)(T + (size_t)c * 8) = o;
}

// ---------------- kernel 2: zero-LDS streaming sim + max/min ----------------
// R18 = R12 (109.6 best) + double-accumulator rotation. Model after 7 probes:
// phase1 ~40 us in EVERY structure (R11-R17); TLP/depth/B-handling/shape/A-dedup
// all exonerated. Remaining mechanism: R12's STEP epilogue (15-fmax chain +
// 2 dependent shfl ~120cyc DS latency + masked store) depends on ITS OWN
// step's 16 MFMAs -> every wave stalls burst->tail every step; matrix pipe
// drains during every epilogue (MfmaUtil 30 + VALU 20 + 50% stall).
//  * Fix: persistent accA/accB. Order: MFMAS(accB) -> EPI(accA) ->
//    MFMAS(accA) -> EPI(accB). Each epilogue runs after a burst it does NOT
//    depend on; in-order issue overlaps fold/shfl with the other acc's MFMAs.
//  * +16 VGPR only (accB); launch_bounds (256,2) and all else held = R12.
// Retained: zero LDS / zero barriers, pre-tiled bf16 A+B, opacity-pinned b,
// swapped MFMA operands, [wn][p][row] pmax (exclusive 64B-line stores).
__global__ __launch_bounds__(256, 2) void phase1(const u16*  __restrict__ T,   // frag-tiled bf16: A then B
                                                 float* __restrict__ pmax,     // [2][256][4096]
                                                 float* __restrict__ pmin)     // [2][4096]
{
    const int tid  = threadIdx.x;
    const int lane = tid & 63;
    const int wave = tid >> 6;
    const int wm   = wave >> 1;       // row half of block's 1024 rows
    const int wn   = wave & 1;        // col half (64 of 128 support cols)
    const int p    = blockIdx.x;      // identity 0..255
    const int h    = blockIdx.y;      // row quarter: rows h*1024..+1023

    // ---- B fragments: 16 one-time global loads -> 64 VGPRs, then OPAQUE ----
    const u16* bbase = T + (size_t)A_CHUNKS * 8
                         + ((size_t)(p * 8 + wn * 4) * 256 + lane) * 8;
    bf16x8 b[4][4];                   // [ni][kk]
#pragma unroll
    for (int ni = 0; ni < 4; ++ni)
#pragma unroll
        for (int kk = 0; kk < 4; ++kk)
            b[ni][kk] = *(const bf16x8*)(bbase + ni * 2048 + kk * 512);
    // Opacity barrier: origin unknowable -> rematerialization impossible.
#pragma unroll
    for (int ni = 0; ni < 4; ++ni)
#pragma unroll
        for (int kk = 0; kk < 4; ++kk)
            asm volatile("" : "+v"(b[ni][kk]));

    // ---- A stream addressing: 32 steps of 16 rows ----
    const int grow0 = h * 64 + wm * 32;                      // global row-group base
    const u16* abase = T + ((size_t)grow0 * 256 + lane) * 8; // +s*2048, +kk*512 (u16)

    // pmax [wn][p][row]: this wave owns rows h*1024 + wm*512 .. +511 at (wn,p)
    float* const pq = pmax + ((size_t)wn * P_IDS + p) * B_DIM + h * 1024 + wm * 512;
    const bool dhit = (h == (p >> 6)) && (wm == ((p >> 5) & 1));
    const int  ssel = p & 31;

#define LOADA(dst, ss) do { const u16* ap = abase + (size_t)(ss) * 2048;         \
        dst[0] = *(const bf16x8*)ap;         dst[1] = *(const bf16x8*)(ap + 512); \
        dst[2] = *(const bf16x8*)(ap + 1024); dst[3] = *(const bf16x8*)(ap + 1536); } while (0)

    // 16 MFMAs into acc (zero-init), operands swapped:
    // D[n][m]: col(lane&15)=A-row (anchor), row(g*4+rr)=B-col (support)
#define MFMAS(acc, areg) do {                                                     \
        acc[0] = z4; acc[1] = z4; acc[2] = z4; acc[3] = z4;                       \
        _Pragma("unroll")                                                         \
        for (int kk = 0; kk < 4; ++kk) {                                          \
            _Pragma("unroll")                                                     \
            for (int ni = 0; ni < 4; ++ni)                                        \
                acc[ni] = __builtin_amdgcn_mfma_f32_16x16x32_bf16(                \
                    b[ni][kk], areg[kk], acc[ni], 0, 0, 0);                       \
        } } while (0)

    // epilogue for a COMPLETED step: balanced-tree fold + 2 shfl + 64B store
#define EPI(acc, ss) do {                                                         \
        float t0 = fmaxf(fmaxf(acc[0][0], acc[0][1]), fmaxf(acc[0][2], acc[0][3]));\
        float t1 = fmaxf(fmaxf(acc[1][0], acc[1][1]), fmaxf(acc[1][2], acc[1][3]));\
        float t2 = fmaxf(fmaxf(acc[2][0], acc[2][1]), fmaxf(acc[2][2], acc[2][3]));\
        float t3 = fmaxf(fmaxf(acc[3][0], acc[3][1]), fmaxf(acc[3][2], acc[3][3]));\
        float mx = fmaxf(fmaxf(t0, t1), fmaxf(t2, t3));                           \
        mx = fmaxf(mx, __shfl_xor(mx, 16, 64));                                   \
        mx = fmaxf(mx, __shfl_xor(mx, 32, 64));                                   \
        if (lane < 16) pq[(ss) * 16 + lane] = mx;                                 \
        if (dhit && (ss) == ssel) {                                               \
            float n0 = fminf(fminf(acc[0][0], acc[0][1]), fminf(acc[0][2], acc[0][3]));\
            float n1 = fminf(fminf(acc[1][0], acc[1][1]), fminf(acc[1][2], acc[1][3]));\
            float n2 = fminf(fminf(acc[2][0], acc[2][1]), fminf(acc[2][2], acc[2][3]));\
            float n3 = fminf(fminf(acc[3][0], acc[3][1]), fminf(acc[3][2], acc[3][3]));\
            float mn = fminf(fminf(n0, n1), fminf(n2, n3));                       \
            mn = fminf(mn, __shfl_xor(mn, 16, 64));                               \
            mn = fminf(mn, __shfl_xor(mn, 32, 64));                               \
            if (lane < 16) pmin[wn * B_DIM + p * 16 + lane] = mn;                 \
        }                                                                         \
    } while (0)

    // ---- rotated pipeline: EPI(X) always follows a burst it does NOT need ----
    bf16x8 aA[4], aB[4];
    f32x4 accA[4], accB[4];
    const f32x4 z4 = {};
    LOADA(aA, 0);
    LOADA(aB, 1);
    MFMAS(accA, aA);                  // step 0 burst in flight
#pragma unroll 1
    for (int s = 0; s < 32; s += 2) {
        MFMAS(accB, aB);              // step s+1 burst
        if (s + 2 < 32) LOADA(aA, s + 2);
        EPI(accA, s);                 // overlaps accB's MFMAs
        if (s + 3 < 32) LOADA(aB, s + 3);
        if (s + 2 < 32) MFMAS(accA, aA);   // step s+2 burst
        EPI(accB, s + 1);             // overlaps accA's MFMAs
    }
#undef LOADA
#undef MFMAS
#undef EPI
}

// ---------------- kernel 3: per-row loss + mean (stripe-transposed reads) ----------------
// 64 blocks x 256 thr. Block owns a 64-row stripe; lane = row, wave owns a
// 64-wide p-range. Every pmax load is a coalesced 256B line (L2-resident).
__global__ __launch_bounds__(256) void phase2(const float* __restrict__ pmax,  // [2][256][4096]
                                              const float* __restrict__ pmin,  // [2][4096]
                                              const int* __restrict__ labels,
                                              float* __restrict__ out) {
    const int tid  = threadIdx.x;
    const int lane = tid & 63;
    const int wave = tid >> 6;
    const int row  = blockIdx.x * 64 + lane;
    const int pid  = labels[row];
    const float* q0 = pmax + (size_t)(wave * 64) * B_DIM + row;   // p = wave*64+j
    const float* q1 = q0 + (size_t)P_IDS * B_DIM;
    float s = 0.f;
#pragma unroll 8
    for (int j = 0; j < 64; ++j) {
        const int p  = wave * 64 + j;
        const float v = fmaxf(q0[(size_t)j * B_DIM], q1[(size_t)j * B_DIM]);
        s += (p == pid) ? 0.f : __expf(v * INV_TEMP);
    }
    __shared__ float part[4][64];
    part[wave][lane] = s;
    __syncthreads();
    if (wave == 0) {
        const float neg = part[0][lane] + part[1][lane] + part[2][lane] + part[3][lane];
        const float mn  = fminf(pmin[row], pmin[B_DIM + row]);
        const float pos = __expf(mn * INV_TEMP);
        float loss = -__logf(pos / (pos + neg + EPS) + EPS);
        loss += __shfl_xor(loss, 1, 64);
        loss += __shfl_xor(loss, 2, 64);
        loss += __shfl_xor(loss, 4, 64);
        loss += __shfl_xor(loss, 8, 64);
        loss += __shfl_xor(loss, 16, 64);
        loss += __shfl_xor(loss, 32, 64);
        if (lane == 0) atomicAdd(out, loss * (1.0f / (float)B_DIM));
    }
}

extern "C" void kernel_launch(void* const* d_in, const int* in_sizes, int n_in,
                              void* d_out, int out_size, void* d_ws, size_t ws_size,
                              hipStream_t stream) {
    const float* feats   = (const float*)d_in[0];   // [4096,128]
    const float* feats_s = (const float*)d_in[1];   // [4096,8,128] fp32
    const int*   labels  = (const int*)d_in[2];     // [4096]
    float* out = (float*)d_out;

    // workspace: T = frag-tiled bf16 A(1 MB)+B(8 MB) | pmax (8 MB) | pmin (32 KB)
    u16* T = (u16*)d_ws;
    float* pmax = (float*)((char*)d_ws + (16u << 20));
    float* pmin = pmax + (size_t)2 * P_IDS * B_DIM;

    hipMemsetAsync(d_out, 0, sizeof(float), stream);
    convert_bf16<<<ALL_CHUNKS / 256, 256, 0, stream>>>(feats, feats_s, T);
    dim3 g1(P_IDS, 4);
    phase1<<<g1, 256, 0, stream>>>(T, pmax, pmin);
    phase2<<<B_DIM / 64, 256, 0, stream>>>(pmax, pmin, labels, out);
}